// Round 4
// baseline (705.751 us; speedup 1.0000x reference)
//
#include <hip/hip_runtime.h>

#define D 128
#define BM 128
#define NREL 8
#define SCAN_BLOCKS 782
#define MPAD (SCAN_BLOCKS * 1024)  // 800768 >= 8*N+1

typedef __attribute__((ext_vector_type(8))) short short8;
typedef __attribute__((ext_vector_type(4))) float f32x4;

typedef const void __attribute__((address_space(1))) gvoid_t;
typedef void __attribute__((address_space(3))) lvoid_t;

__device__ inline unsigned short f2bf(float f) {
  unsigned u = __builtin_bit_cast(unsigned, f);
  u += 0x7FFFu + ((u >> 16) & 1u);
  return (unsigned short)(u >> 16);
}

__device__ inline void gload16(const void* g, void* l) {
  __builtin_amdgcn_global_load_lds((gvoid_t*)g, (lvoid_t*)l, 16, 0, 0);
}

// packed 2xbf16 atomic add into LDS (DS pipe, no VALU unpack)
__device__ inline void ds_pk_add(void* lptr, unsigned data) {
  asm volatile("ds_pk_add_bf16 %0, %1" ::"v"((lvoid_t*)lptr), "v"(data)
               : "memory");
}

// emb f32 -> xb bf16, compact [N][128]
__global__ __launch_bounds__(256) void cvt_x(const float* __restrict__ x,
                                             unsigned short* __restrict__ dst,
                                             long total /* = N*32 float4 */) {
  long i = (long)blockIdx.x * 256 + threadIdx.x;
  if (i >= total) return;
  float4 v = reinterpret_cast<const float4*>(x)[i];
  unsigned lo = (unsigned)f2bf(v.x) | ((unsigned)f2bf(v.y) << 16);
  unsigned hi = (unsigned)f2bf(v.z) | ((unsigned)f2bf(v.w) << 16);
  reinterpret_cast<uint2*>(dst)[i] = make_uint2(lo, hi);
}

// Pre-swizzled B tiles for BOTH layers. Physical element (l, r, c, pb):
// logical k = pb ^ ((c&15)<<3); value = W[r][k][c] (r<8) else SW[k][c].
__global__ __launch_bounds__(256) void wcvt(const float* __restrict__ W1,
                                            const float* __restrict__ SL1,
                                            const float* __restrict__ W2,
                                            const float* __restrict__ SL2,
                                            unsigned short* __restrict__ Btr) {
  int idx = blockIdx.x * 256 + threadIdx.x;
  if (idx >= 2 * 9 * D * D) return;
  int l = idx >= 9 * D * D;
  int t = idx - l * 9 * D * D;
  int r = t >> 14;
  int rem = t & 16383;
  int c = rem >> 7;
  int pb = rem & 127;
  int k = pb ^ ((c & 15) << 3);
  const float* W = l ? W2 : W1;
  const float* SL = l ? SL2 : SL1;
  float v = (r < NREL) ? W[((r * D) + k) * D + c] : SL[k * D + c];
  Btr[idx] = f2bf(v);
}

__global__ __launch_bounds__(256) void hist_kernel(const int* __restrict__ dst,
                                                   const int* __restrict__ rel,
                                                   int* __restrict__ counts,
                                                   int E, int N) {
  int e = blockIdx.x * 256 + threadIdx.x;
  if (e >= E) return;
  atomicAdd(&counts[rel[e] * N + dst[e]], 1);
}

__global__ __launch_bounds__(256) void scan1(const int* __restrict__ in,
                                             int* __restrict__ out,
                                             int* __restrict__ bsum) {
  __shared__ int tmp[256];
  int t = threadIdx.x;
  long base = (long)blockIdx.x * 1024 + t * 4;
  int v[4];
  int s = 0;
#pragma unroll
  for (int j = 0; j < 4; ++j) {
    v[j] = in[base + j];
    s += v[j];
  }
  tmp[t] = s;
  __syncthreads();
  for (int off = 1; off < 256; off <<= 1) {
    int x = (t >= off) ? tmp[t - off] : 0;
    __syncthreads();
    tmp[t] += x;
    __syncthreads();
  }
  int run = tmp[t] - s;
  if (t == 255) bsum[blockIdx.x] = tmp[255];
#pragma unroll
  for (int j = 0; j < 4; ++j) {
    out[base + j] = run;
    run += v[j];
  }
}

__global__ __launch_bounds__(1024) void scan_top(int* __restrict__ bsum, int nb) {
  __shared__ int tmp[1024];
  int t = threadIdx.x;
  int v = (t < nb) ? bsum[t] : 0;
  tmp[t] = v;
  __syncthreads();
  for (int off = 1; off < 1024; off <<= 1) {
    int x = (t >= off) ? tmp[t - off] : 0;
    __syncthreads();
    tmp[t] += x;
    __syncthreads();
  }
  if (t < nb) bsum[t] = tmp[t] - v;
}

__global__ __launch_bounds__(256) void scan_add(int* __restrict__ starts,
                                                int* __restrict__ cursor,
                                                const int* __restrict__ bsum) {
  long base = (long)blockIdx.x * 1024 + threadIdx.x * 4;
  int add = bsum[blockIdx.x];
#pragma unroll
  for (int j = 0; j < 4; ++j) {
    int v = starts[base + j] + add;
    starts[base + j] = v;
    cursor[base + j] = v;
  }
}

__global__ __launch_bounds__(256) void reorder(const int* __restrict__ src,
                                               const int* __restrict__ dst,
                                               const int* __restrict__ rel,
                                               int* __restrict__ cursor,
                                               int2* __restrict__ es, int E,
                                               int N) {
  int e = blockIdx.x * 256 + threadIdx.x;
  if (e >= E) return;
  int pos = atomicAdd(&cursor[rel[e] * N + dst[e]], 1);
  es[pos] = make_int2(src[e], dst[e]);
}

// Fused RGCN layer: per 128-row block, per relation r: edge-parallel gather
// of x[src] into swizzled bf16 A-tile via ds_pk_add_bf16, then MFMA vs W[r].
// r=8 = self-loop (A = xb rows via pre-swizzled-source global_load_lds).
__global__ __launch_bounds__(256) void fused_layer(
    const unsigned short* __restrict__ xb, const int* __restrict__ starts,
    const int2* __restrict__ es, const unsigned short* __restrict__ Btr,
    const float* __restrict__ bias, unsigned short* __restrict__ xout_b,
    float* __restrict__ outf, int N) {
  __shared__ char As[32768];  // 128 rows x 256B, XOR-swizzled ((row&15)<<4)
  __shared__ char Bs[32768];

  const int tid = threadIdx.x;
  const int wave = tid >> 6, lane = tid & 63;
  const int wm = wave >> 1, wn = wave & 1;
  const int l15 = lane & 15, lq = lane >> 4;
  const int row0 = blockIdx.x * BM;
  const int rowend = (row0 + BM < N) ? (row0 + BM) : N;
  const int eg = tid >> 2, cb = tid & 3;

  f32x4 acc[4][4];
#pragma unroll
  for (int m = 0; m < 4; ++m)
#pragma unroll
    for (int n = 0; n < 4; ++n)
#pragma unroll
      for (int q = 0; q < 4; ++q) acc[m][n][q] = 0.f;

  for (int r = 0; r < 9; ++r) {
    __syncthreads();  // previous MFMA reads done before overwriting As/Bs
    // stage B tile (pre-swizzled in global -> linear LDS)
    const char* bsrc = reinterpret_cast<const char*>(Btr) + r * 32768;
#pragma unroll
    for (int i = 0; i < 8; ++i) {
      int o = i * 4096 + tid * 16;
      gload16(bsrc + o, Bs + o);
    }
    if (r < NREL) {
      // zero A tile
#pragma unroll
      for (int i = 0; i < 8; ++i)
        *reinterpret_cast<int4*>(As + i * 4096 + tid * 16) =
            make_int4(0, 0, 0, 0);
      __syncthreads();
      int e0 = starts[r * N + row0];
      int e1 = starts[r * N + rowend];
      for (int eb = e0; eb < e1; eb += 64) {
        int e = eb + eg;
        if (e < e1) {
          int2 sd = es[e];
          const uint4* p =
              reinterpret_cast<const uint4*>(xb + (size_t)sd.x * D) + cb * 4;
          int dstl = sd.y - row0;
          int swz = (dstl & 15) << 4;
          char* rowp = As + dstl * 256;
          uint4 u0 = p[0], u1 = p[1], u2 = p[2], u3 = p[3];
#pragma unroll
          for (int j = 0; j < 4; ++j) {
            uint4 u = (j == 0) ? u0 : (j == 1) ? u1 : (j == 2) ? u2 : u3;
            char* bp = rowp + (((cb * 64 + j * 16)) ^ swz);
            ds_pk_add(bp + 0, u.x);
            ds_pk_add(bp + 4, u.y);
            ds_pk_add(bp + 8, u.z);
            ds_pk_add(bp + 12, u.w);
          }
        }
      }
    } else {
      // self-loop: A = xb rows, pre-swizzled per-lane global source
#pragma unroll
      for (int i = 0; i < 8; ++i) {
        int o = i * 4096 + tid * 16;
        int row = o >> 8, b = o & 255;
        int grow = row0 + row;
        if (grow >= N) grow = N - 1;
        int sb = b ^ ((row & 15) << 4);
        gload16(reinterpret_cast<const char*>(xb + (size_t)grow * D) + sb,
                As + o);
      }
    }
    __syncthreads();
    // MFMA over K=128
#pragma unroll
    for (int kh = 0; kh < 2; ++kh) {
      short8 af[4][2], bfr[4][2];
#pragma unroll
      for (int m = 0; m < 4; ++m)
#pragma unroll
        for (int k2 = 0; k2 < 2; ++k2) {
          int rr = wm * 64 + m * 16 + l15;
          int b = ((kh * 2 + k2) * 64 + lq * 16) ^ ((rr & 15) << 4);
          af[m][k2] = *reinterpret_cast<const short8*>(As + rr * 256 + b);
        }
#pragma unroll
      for (int n = 0; n < 4; ++n)
#pragma unroll
        for (int k2 = 0; k2 < 2; ++k2) {
          int rr = wn * 64 + n * 16 + l15;
          int b = ((kh * 2 + k2) * 64 + lq * 16) ^ ((rr & 15) << 4);
          bfr[n][k2] = *reinterpret_cast<const short8*>(Bs + rr * 256 + b);
        }
#pragma unroll
      for (int m = 0; m < 4; ++m)
#pragma unroll
        for (int n = 0; n < 4; ++n) {
          acc[m][n] = __builtin_amdgcn_mfma_f32_16x16x32_bf16(
              af[m][0], bfr[n][0], acc[m][n], 0, 0, 0);
          acc[m][n] = __builtin_amdgcn_mfma_f32_16x16x32_bf16(
              af[m][1], bfr[n][1], acc[m][n], 0, 0, 0);
        }
    }
  }

  // epilogue: C/D layout col = lane&15, row = (lane>>4)*4 + reg
#pragma unroll
  for (int n = 0; n < 4; ++n) {
    int col = wn * 64 + n * 16 + l15;
    float bv = bias[col];
#pragma unroll
    for (int m = 0; m < 4; ++m) {
      int rbase = row0 + wm * 64 + m * 16 + lq * 4;
#pragma unroll
      for (int q = 0; q < 4; ++q) {
        int row = rbase + q;
        if (row < N) {
          float v = fmaxf(acc[m][n][q] + bv, 0.f);
          if (outf)
            outf[(size_t)row * D + col] = v;
          else
            xout_b[(size_t)row * D + col] = f2bf(v);
        }
      }
    }
  }
}

extern "C" void kernel_launch(void* const* d_in, const int* in_sizes, int n_in,
                              void* d_out, int out_size, void* d_ws, size_t ws_size,
                              hipStream_t stream) {
  const float* emb = (const float*)d_in[0];
  const float* W1 = (const float*)d_in[1];
  const float* SL1 = (const float*)d_in[2];
  const float* B1 = (const float*)d_in[3];
  const float* W2 = (const float*)d_in[4];
  const float* SL2 = (const float*)d_in[5];
  const float* B2 = (const float*)d_in[6];
  const int* eidx = (const int*)d_in[7];
  const int* etyp = (const int*)d_in[8];
  const int N = in_sizes[0] / D;
  const int E = in_sizes[8];
  const int* srcp = eidx;
  const int* dstp = eidx + E;
  float* outp = (float*)d_out;

  char* w = (char*)d_ws;
  unsigned short* xb0 = (unsigned short*)w;            // N*128 bf16
  unsigned short* xb1 = xb0 + (size_t)N * D;           // N*128 bf16
  unsigned short* Btr = xb1 + (size_t)N * D;           // 2*9*128*128 bf16 (pre-swizzled)
  int* counts = (int*)(Btr + 2 * 9 * D * D);           // MPAD ints
  int* starts = counts + MPAD;
  int* cursor = starts + MPAD;
  int* bsum = cursor + MPAD;                           // 1024 ints
  int2* es = (int2*)(bsum + 1024);                     // E int2 (src,dst)

  const int eb = (E + 255) / 256;
  const int gm_blocks = (N + BM - 1) / BM;

  // preprocessing (graph structure shared by both layers)
  hipMemsetAsync(counts, 0, (size_t)MPAD * 4, stream);
  cvt_x<<<(int)(((long)N * 32 + 255) / 256), 256, 0, stream>>>(emb, xb0,
                                                               (long)N * 32);
  wcvt<<<(2 * 9 * D * D + 255) / 256, 256, 0, stream>>>(W1, SL1, W2, SL2, Btr);
  hist_kernel<<<eb, 256, 0, stream>>>(dstp, etyp, counts, E, N);
  scan1<<<SCAN_BLOCKS, 256, 0, stream>>>(counts, starts, bsum);
  scan_top<<<1, 1024, 0, stream>>>(bsum, SCAN_BLOCKS);
  scan_add<<<SCAN_BLOCKS, 256, 0, stream>>>(starts, cursor, bsum);
  reorder<<<eb, 256, 0, stream>>>(srcp, dstp, etyp, cursor, es, E, N);

  // layer 1: xb0 -> xb1 (bf16); layer 2: xb1 -> outp (f32)
  fused_layer<<<gm_blocks, 256, 0, stream>>>(xb0, starts, es, Btr, B1, xb1,
                                             nullptr, N);
  fused_layer<<<gm_blocks, 256, 0, stream>>>(
      xb1, starts, es, Btr + 9 * D * D, B2, nullptr, outp, N);
}

// Round 5
// 702.013 us; speedup vs baseline: 1.0053x; 1.0053x over previous
//
#include <hip/hip_runtime.h>

#define D 128
#define BM 128
#define NREL 8
#define SCAN_BLOCKS 782
#define MPAD (SCAN_BLOCKS * 1024)  // 800768 >= 8*N+1

typedef __attribute__((ext_vector_type(8))) short short8;
typedef __attribute__((ext_vector_type(4))) float f32x4;

typedef const void __attribute__((address_space(1))) gvoid_t;
typedef void __attribute__((address_space(3))) lvoid_t;

__device__ inline unsigned short f2bf(float f) {
  unsigned u = __builtin_bit_cast(unsigned, f);
  u += 0x7FFFu + ((u >> 16) & 1u);
  return (unsigned short)(u >> 16);
}

__device__ inline void gload16(const void* g, void* l) {
  __builtin_amdgcn_global_load_lds((gvoid_t*)g, (lvoid_t*)l, 16, 0, 0);
}

// packed 2xbf16 LDS atomic add. NO memory clobber: ordering vs the MFMA
// ds_reads is enforced by an explicit lgkmcnt(0)+sched_barrier before the
// barrier (round-4 lesson: the clobber forced full drains per op).
__device__ inline void ds_pk_add(void* lptr, unsigned data) {
  asm volatile("ds_pk_add_bf16 %0, %1" ::"v"((lvoid_t*)lptr), "v"(data));
}

// emb f32 -> xb bf16, compact [N][128]
__global__ __launch_bounds__(256) void cvt_x(const float* __restrict__ x,
                                             unsigned short* __restrict__ dst,
                                             long total /* = N*32 float4 */) {
  long i = (long)blockIdx.x * 256 + threadIdx.x;
  if (i >= total) return;
  float4 v = reinterpret_cast<const float4*>(x)[i];
  unsigned lo = (unsigned)f2bf(v.x) | ((unsigned)f2bf(v.y) << 16);
  unsigned hi = (unsigned)f2bf(v.z) | ((unsigned)f2bf(v.w) << 16);
  reinterpret_cast<uint2*>(dst)[i] = make_uint2(lo, hi);
}

// Pre-swizzled B tiles for BOTH layers. Physical element (l, r, c, pb):
// logical k = pb ^ ((c&15)<<3); value = W[r][k][c] (r<8) else SW[k][c].
__global__ __launch_bounds__(256) void wcvt(const float* __restrict__ W1,
                                            const float* __restrict__ SL1,
                                            const float* __restrict__ W2,
                                            const float* __restrict__ SL2,
                                            unsigned short* __restrict__ Btr) {
  int idx = blockIdx.x * 256 + threadIdx.x;
  if (idx >= 2 * 9 * D * D) return;
  int l = idx >= 9 * D * D;
  int t = idx - l * 9 * D * D;
  int r = t >> 14;
  int rem = t & 16383;
  int c = rem >> 7;
  int pb = rem & 127;
  int k = pb ^ ((c & 15) << 3);
  const float* W = l ? W2 : W1;
  const float* SL = l ? SL2 : SL1;
  float v = (r < NREL) ? W[((r * D) + k) * D + c] : SL[k * D + c];
  Btr[idx] = f2bf(v);
}

__global__ __launch_bounds__(256) void hist_kernel(const int* __restrict__ dst,
                                                   const int* __restrict__ rel,
                                                   int* __restrict__ counts,
                                                   int E, int N) {
  int e = blockIdx.x * 256 + threadIdx.x;
  if (e >= E) return;
  atomicAdd(&counts[rel[e] * N + dst[e]], 1);
}

__global__ __launch_bounds__(256) void scan1(const int* __restrict__ in,
                                             int* __restrict__ out,
                                             int* __restrict__ bsum) {
  __shared__ int tmp[256];
  int t = threadIdx.x;
  long base = (long)blockIdx.x * 1024 + t * 4;
  int v[4];
  int s = 0;
#pragma unroll
  for (int j = 0; j < 4; ++j) {
    v[j] = in[base + j];
    s += v[j];
  }
  tmp[t] = s;
  __syncthreads();
  for (int off = 1; off < 256; off <<= 1) {
    int x = (t >= off) ? tmp[t - off] : 0;
    __syncthreads();
    tmp[t] += x;
    __syncthreads();
  }
  int run = tmp[t] - s;
  if (t == 255) bsum[blockIdx.x] = tmp[255];
#pragma unroll
  for (int j = 0; j < 4; ++j) {
    out[base + j] = run;
    run += v[j];
  }
}

__global__ __launch_bounds__(1024) void scan_top(int* __restrict__ bsum, int nb) {
  __shared__ int tmp[1024];
  int t = threadIdx.x;
  int v = (t < nb) ? bsum[t] : 0;
  tmp[t] = v;
  __syncthreads();
  for (int off = 1; off < 1024; off <<= 1) {
    int x = (t >= off) ? tmp[t - off] : 0;
    __syncthreads();
    tmp[t] += x;
    __syncthreads();
  }
  if (t < nb) bsum[t] = tmp[t] - v;
}

__global__ __launch_bounds__(256) void scan_add(int* __restrict__ starts,
                                                int* __restrict__ cursor,
                                                const int* __restrict__ bsum) {
  long base = (long)blockIdx.x * 1024 + threadIdx.x * 4;
  int add = bsum[blockIdx.x];
#pragma unroll
  for (int j = 0; j < 4; ++j) {
    int v = starts[base + j] + add;
    starts[base + j] = v;
    cursor[base + j] = v;
  }
}

__global__ __launch_bounds__(256) void reorder(const int* __restrict__ src,
                                               const int* __restrict__ dst,
                                               const int* __restrict__ rel,
                                               int* __restrict__ cursor,
                                               int2* __restrict__ es, int E,
                                               int N) {
  int e = blockIdx.x * 256 + threadIdx.x;
  if (e >= E) return;
  int pos = atomicAdd(&cursor[rel[e] * N + dst[e]], 1);
  es[pos] = make_int2(src[e], dst[e]);
}

// Fused RGCN layer: per 128-row block, per relation r: pipelined edge-parallel
// gather of x[src] into swizzled bf16 A-tile via ds_pk_add_bf16, then MFMA
// with B fragments read from global (pre-swizzled, L2-resident).
// r=8 = self-loop (A = xb rows via pre-swizzled-source global_load_lds).
__global__ __launch_bounds__(256) void fused_layer(
    const unsigned short* __restrict__ xb, const int* __restrict__ starts,
    const int2* __restrict__ es, const unsigned short* __restrict__ Btr,
    const float* __restrict__ bias, unsigned short* __restrict__ xout_b,
    float* __restrict__ outf, int N) {
  __shared__ char As[32768];  // 128 rows x 256B, XOR-swizzled ((row&15)<<4)

  const int tid = threadIdx.x;
  const int wave = tid >> 6, lane = tid & 63;
  const int wm = wave >> 1, wn = wave & 1;
  const int l15 = lane & 15, lq = lane >> 4;
  const int row0 = blockIdx.x * BM;
  const int rowend = (row0 + BM < N) ? (row0 + BM) : N;
  const int eg = tid >> 2, cb = tid & 3;
  const char* BtrB = reinterpret_cast<const char*>(Btr);

  f32x4 acc[4][4];
#pragma unroll
  for (int m = 0; m < 4; ++m)
#pragma unroll
    for (int n = 0; n < 4; ++n)
#pragma unroll
      for (int q = 0; q < 4; ++q) acc[m][n][q] = 0.f;

  for (int r = 0; r < 9; ++r) {
    __syncthreads();  // previous MFMA reads of As done before overwrite
    if (r < NREL) {
      // zero A tile
#pragma unroll
      for (int i = 0; i < 8; ++i)
        *reinterpret_cast<int4*>(As + i * 4096 + tid * 16) =
            make_int4(0, 0, 0, 0);
      __syncthreads();
      const int e0 = starts[r * N + row0];
      const int e1 = starts[r * N + rowend];
      // 2-stage pipelined gather: 64 edges/batch, 4 lanes/edge (64B each)
      int2 sd;
      uint4 u0, u1, u2, u3;
      if (e0 + eg < e1) {
        sd = es[e0 + eg];
        const uint4* p =
            reinterpret_cast<const uint4*>(xb + (size_t)sd.x * D) + cb * 4;
        u0 = p[0]; u1 = p[1]; u2 = p[2]; u3 = p[3];
      }
      for (int ebs = e0; ebs < e1; ebs += 64) {
        const bool curv = (ebs + eg) < e1;
        int2 sdc = sd;
        uint4 c0 = u0, c1 = u1, c2 = u2, c3 = u3;
        const int en = ebs + 64 + eg;
        if (en < e1) {  // prefetch next batch (hoistable above the DS asm)
          sd = es[en];
          const uint4* p =
              reinterpret_cast<const uint4*>(xb + (size_t)sd.x * D) + cb * 4;
          u0 = p[0]; u1 = p[1]; u2 = p[2]; u3 = p[3];
        }
        if (curv) {
          const int dstl = sdc.y - row0;
          const int swz = (dstl & 15) << 4;
          char* rowp = As + dstl * 256;
          char* bp0 = rowp + ((cb * 64 + 0) ^ swz);
          char* bp1 = rowp + ((cb * 64 + 16) ^ swz);
          char* bp2 = rowp + ((cb * 64 + 32) ^ swz);
          char* bp3 = rowp + ((cb * 64 + 48) ^ swz);
          ds_pk_add(bp0 + 0, c0.x); ds_pk_add(bp0 + 4, c0.y);
          ds_pk_add(bp0 + 8, c0.z); ds_pk_add(bp0 + 12, c0.w);
          ds_pk_add(bp1 + 0, c1.x); ds_pk_add(bp1 + 4, c1.y);
          ds_pk_add(bp1 + 8, c1.z); ds_pk_add(bp1 + 12, c1.w);
          ds_pk_add(bp2 + 0, c2.x); ds_pk_add(bp2 + 4, c2.y);
          ds_pk_add(bp2 + 8, c2.z); ds_pk_add(bp2 + 12, c2.w);
          ds_pk_add(bp3 + 0, c3.x); ds_pk_add(bp3 + 4, c3.y);
          ds_pk_add(bp3 + 8, c3.z); ds_pk_add(bp3 + 12, c3.w);
        }
      }
      // make all DS atomics visible before the barrier (asm ops are
      // invisible to the compiler's lgkmcnt tracking)
      asm volatile("s_waitcnt lgkmcnt(0)");
      __builtin_amdgcn_sched_barrier(0);
    } else {
      // self-loop: A = xb rows, pre-swizzled per-lane global source
#pragma unroll
      for (int i = 0; i < 8; ++i) {
        int o = i * 4096 + tid * 16;
        int row = o >> 8, b = o & 255;
        int grow = row0 + row;
        if (grow >= N) grow = N - 1;
        int sb = b ^ ((row & 15) << 4);
        gload16(reinterpret_cast<const char*>(xb + (size_t)grow * D) + sb,
                As + o);
      }
    }
    __syncthreads();
    // MFMA over K=128; B fragments straight from global (L2-resident Btr)
#pragma unroll
    for (int kh = 0; kh < 2; ++kh) {
      short8 af[4][2], bfr[4][2];
#pragma unroll
      for (int n = 0; n < 4; ++n)
#pragma unroll
        for (int k2 = 0; k2 < 2; ++k2) {
          int rr = wn * 64 + n * 16 + l15;
          int b = ((kh * 2 + k2) * 64 + lq * 16) ^ ((rr & 15) << 4);
          bfr[n][k2] = *reinterpret_cast<const short8*>(
              BtrB + (size_t)r * 32768 + rr * 256 + b);
        }
#pragma unroll
      for (int m = 0; m < 4; ++m)
#pragma unroll
        for (int k2 = 0; k2 < 2; ++k2) {
          int rr = wm * 64 + m * 16 + l15;
          int b = ((kh * 2 + k2) * 64 + lq * 16) ^ ((rr & 15) << 4);
          af[m][k2] = *reinterpret_cast<const short8*>(As + rr * 256 + b);
        }
#pragma unroll
      for (int m = 0; m < 4; ++m)
#pragma unroll
        for (int n = 0; n < 4; ++n) {
          acc[m][n] = __builtin_amdgcn_mfma_f32_16x16x32_bf16(
              af[m][0], bfr[n][0], acc[m][n], 0, 0, 0);
          acc[m][n] = __builtin_amdgcn_mfma_f32_16x16x32_bf16(
              af[m][1], bfr[n][1], acc[m][n], 0, 0, 0);
        }
    }
  }

  // epilogue: C/D layout col = lane&15, row = (lane>>4)*4 + reg
#pragma unroll
  for (int n = 0; n < 4; ++n) {
    int col = wn * 64 + n * 16 + l15;
    float bv = bias[col];
#pragma unroll
    for (int m = 0; m < 4; ++m) {
      int rbase = row0 + wm * 64 + m * 16 + lq * 4;
#pragma unroll
      for (int q = 0; q < 4; ++q) {
        int row = rbase + q;
        if (row < N) {
          float v = fmaxf(acc[m][n][q] + bv, 0.f);
          if (outf)
            outf[(size_t)row * D + col] = v;
          else
            xout_b[(size_t)row * D + col] = f2bf(v);
        }
      }
    }
  }
}

extern "C" void kernel_launch(void* const* d_in, const int* in_sizes, int n_in,
                              void* d_out, int out_size, void* d_ws, size_t ws_size,
                              hipStream_t stream) {
  const float* emb = (const float*)d_in[0];
  const float* W1 = (const float*)d_in[1];
  const float* SL1 = (const float*)d_in[2];
  const float* B1 = (const float*)d_in[3];
  const float* W2 = (const float*)d_in[4];
  const float* SL2 = (const float*)d_in[5];
  const float* B2 = (const float*)d_in[6];
  const int* eidx = (const int*)d_in[7];
  const int* etyp = (const int*)d_in[8];
  const int N = in_sizes[0] / D;
  const int E = in_sizes[8];
  const int* srcp = eidx;
  const int* dstp = eidx + E;
  float* outp = (float*)d_out;

  char* w = (char*)d_ws;
  unsigned short* xb0 = (unsigned short*)w;            // N*128 bf16
  unsigned short* xb1 = xb0 + (size_t)N * D;           // N*128 bf16
  unsigned short* Btr = xb1 + (size_t)N * D;           // 2*9*128*128 bf16 (pre-swizzled)
  int* counts = (int*)(Btr + 2 * 9 * D * D);           // MPAD ints
  int* starts = counts + MPAD;
  int* cursor = starts + MPAD;
  int* bsum = cursor + MPAD;                           // 1024 ints
  int2* es = (int2*)(bsum + 1024);                     // E int2 (src,dst)

  const int eb = (E + 255) / 256;
  const int gm_blocks = (N + BM - 1) / BM;

  // preprocessing (graph structure shared by both layers)
  hipMemsetAsync(counts, 0, (size_t)MPAD * 4, stream);
  cvt_x<<<(int)(((long)N * 32 + 255) / 256), 256, 0, stream>>>(emb, xb0,
                                                               (long)N * 32);
  wcvt<<<(2 * 9 * D * D + 255) / 256, 256, 0, stream>>>(W1, SL1, W2, SL2, Btr);
  hist_kernel<<<eb, 256, 0, stream>>>(dstp, etyp, counts, E, N);
  scan1<<<SCAN_BLOCKS, 256, 0, stream>>>(counts, starts, bsum);
  scan_top<<<1, 1024, 0, stream>>>(bsum, SCAN_BLOCKS);
  scan_add<<<SCAN_BLOCKS, 256, 0, stream>>>(starts, cursor, bsum);
  reorder<<<eb, 256, 0, stream>>>(srcp, dstp, etyp, cursor, es, E, N);

  // layer 1: xb0 -> xb1 (bf16); layer 2: xb1 -> outp (f32)
  fused_layer<<<gm_blocks, 256, 0, stream>>>(xb0, starts, es, Btr, B1, xb1,
                                             nullptr, N);
  fused_layer<<<gm_blocks, 256, 0, stream>>>(
      xb1, starts, es, Btr + 9 * D * D, B2, nullptr, outp, N);
}